// Round 1
// baseline (479.061 us; speedup 1.0000x reference)
//
#include <hip/hip_runtime.h>

#define D 64
#define SH 10             // bucket = key >> SH; 1024 keys/bucket
#define BK 1024
#define NBLK 256          // blocks for sort passes A1/A2

typedef _Float16 half4v __attribute__((ext_vector_type(4)));
typedef _Float16 half8 __attribute__((ext_vector_type(8)));
typedef float f32x4 __attribute__((ext_vector_type(4)));

__device__ __forceinline__ float fast_tanh(float x) {
    float e = __expf(2.f * x);
    return 1.f - 2.f * __builtin_amdgcn_rcpf(e + 1.f);
}

// ---------------------------------------------------------------------------
// Split-fp16 MFMA GEMM: C[M,64] = A[M,64] @ W[64,64], fp32-accurate via
// A=Ah+Ar, W=Wh+Wr (fp16 hi + fp16 residual); C ≈ AhWh + ArWh + AhWr.
// GATE: C = tanh(C * gate) (gate may alias Cf — so NO restrict on gate/Cf).
// WF: fp32 out. WH: fp16 out.
// Block: 64 rows, 4 waves; wave rt -> rows rt*16..+15. W staged transposed.
// ---------------------------------------------------------------------------
template <int GATE, int WF, int WH>
__global__ __launch_bounds__(256) void gemm64(const float* __restrict__ A,
                                              const float* __restrict__ W,
                                              const float* gate,
                                              float* Cf,
                                              _Float16* Ch, int M) {
    __shared__ _Float16 Ahi[64 * 72];
    __shared__ _Float16 Are[64 * 72];
    __shared__ _Float16 Whi[64 * 72];   // transposed: [n][k]
    __shared__ _Float16 Wre[64 * 72];
    const int tid = threadIdx.x;
    const int base = blockIdx.x * 64;

#pragma unroll
    for (int i = 0; i < 4; ++i) {
        int idx4 = (tid + i * 256) * 4;          // 0..4095 step 4
        int r = idx4 >> 6, k = idx4 & 63;
        float4 va = make_float4(0.f, 0.f, 0.f, 0.f);
        if (base + r < M) va = *(const float4*)&A[(size_t)(base + r) * D + k];
        half4v hh, hr;
        hh.x = (_Float16)va.x; hr.x = (_Float16)(va.x - (float)hh.x);
        hh.y = (_Float16)va.y; hr.y = (_Float16)(va.y - (float)hh.y);
        hh.z = (_Float16)va.z; hr.z = (_Float16)(va.z - (float)hh.z);
        hh.w = (_Float16)va.w; hr.w = (_Float16)(va.w - (float)hh.w);
        *(half4v*)&Ahi[r * 72 + k] = hh;
        *(half4v*)&Are[r * 72 + k] = hr;
        // W row-major [k][n] -> staged transposed [n][k]
        int wk = idx4 >> 6, wn = idx4 & 63;
        float4 vw = *(const float4*)&W[idx4];
#pragma unroll
        for (int j = 0; j < 4; ++j) {
            float w = (&vw.x)[j];
            _Float16 h = (_Float16)w;
            Whi[(wn + j) * 72 + wk] = h;
            Wre[(wn + j) * 72 + wk] = (_Float16)(w - (float)h);
        }
    }
    __syncthreads();

    const int lane = tid & 63;
    const int rt = tid >> 6;          // wave's 16-row tile
    const int m = lane & 15;          // A row in tile / C col in tile
    const int q = lane >> 4;          // k-subchunk

    f32x4 acc[4] = {};
#pragma unroll
    for (int kc = 0; kc < 64; kc += 32) {
        half8 ah = *(const half8*)&Ahi[(rt * 16 + m) * 72 + kc + q * 8];
        half8 ar = *(const half8*)&Are[(rt * 16 + m) * 72 + kc + q * 8];
#pragma unroll
        for (int ct = 0; ct < 4; ++ct) {
            half8 bh = *(const half8*)&Whi[(ct * 16 + m) * 72 + kc + q * 8];
            half8 br = *(const half8*)&Wre[(ct * 16 + m) * 72 + kc + q * 8];
            acc[ct] = __builtin_amdgcn_mfma_f32_16x16x32_f16(ah, bh, acc[ct], 0, 0, 0);
            acc[ct] = __builtin_amdgcn_mfma_f32_16x16x32_f16(ar, bh, acc[ct], 0, 0, 0);
            acc[ct] = __builtin_amdgcn_mfma_f32_16x16x32_f16(ah, br, acc[ct], 0, 0, 0);
        }
    }

#pragma unroll
    for (int r_ = 0; r_ < 4; ++r_) {
        int row = base + rt * 16 + q * 4 + r_;
        if (row < M) {
#pragma unroll
            for (int ct = 0; ct < 4; ++ct) {
                size_t off = (size_t)row * D + ct * 16 + m;
                float v = acc[ct][r_];
                if (GATE) v = fast_tanh(v * gate[off]);
                if (WF) Cf[off] = v;
                if (WH) Ch[off] = (_Float16)v;
            }
        }
    }
}

// --------------------- zero-global-atomic counting sort ---------------------
__global__ __launch_bounds__(256) void sort_hist(const int* __restrict__ keys,
                                                 int* __restrict__ cmat,
                                                 int n, int B, int ipb) {
    __shared__ int h[256];
    const int tid = threadIdx.x;
    for (int i = tid; i < B; i += 256) h[i] = 0;
    __syncthreads();
    const int start = blockIdx.x * ipb;
    const int end = (start + ipb < n) ? start + ipb : n;
    for (int i = start + tid; i < end; i += 256)
        atomicAdd(&h[keys[i] >> SH], 1);
    __syncthreads();
    for (int b = tid; b < B; b += 256) cmat[b * NBLK + blockIdx.x] = h[b];
}

__global__ __launch_bounds__(256) void scan1(const int* __restrict__ src,
                                             int* __restrict__ dst,
                                             int* __restrict__ bsums, int n) {
    __shared__ int s[256];
    const int t = threadIdx.x;
    const int base = blockIdx.x * 1024 + t * 4;
    int v[4];
#pragma unroll
    for (int j = 0; j < 4; ++j) v[j] = (base + j < n) ? src[base + j] : 0;
    int tsum = v[0] + v[1] + v[2] + v[3];
    s[t] = tsum;
    __syncthreads();
    for (int o = 1; o < 256; o <<= 1) {
        int x = (t >= o) ? s[t - o] : 0;
        __syncthreads();
        s[t] += x;
        __syncthreads();
    }
    int run = s[t] - tsum;
    if (t == 255) bsums[blockIdx.x] = s[255];
#pragma unroll
    for (int j = 0; j < 4; ++j) {
        if (base + j < n) dst[base + j] = run;
        run += v[j];
    }
}

// Fused: exclusive-scan the per-block sums in LDS (redundantly per block),
// then add to this block's 256 elements. Replaces scan2+scan3 (one fewer
// dispatch + one fewer serialization point in the sort chain).
__global__ __launch_bounds__(256) void scan23(int* __restrict__ a,
                                              const int* __restrict__ bsums,
                                              int n, int nb) {
    __shared__ int sb[256];
    const int t = threadIdx.x;
    int v = (t < nb) ? bsums[t] : 0;
    sb[t] = v;
    __syncthreads();
    for (int o = 1; o < 256; o <<= 1) {
        int x = (t >= o) ? sb[t - o] : 0;
        __syncthreads();
        sb[t] += x;
        __syncthreads();
    }
    int incl = sb[t];
    __syncthreads();
    sb[t] = incl - v;          // exclusive block prefix
    __syncthreads();
    int i = blockIdx.x * 256 + t;
    if (i < n) a[i] += sb[i >> 10];
}

__global__ __launch_bounds__(256) void sort_scatter(const int* __restrict__ keys,
                                                    const int* __restrict__ vals,
                                                    const int* __restrict__ cscan,
                                                    int* __restrict__ bucketed,
                                                    int n, int B, int ipb) {
    __shared__ int cur[256];
    const int tid = threadIdx.x;
    for (int i = tid; i < B; i += 256) cur[i] = cscan[i * NBLK + blockIdx.x];
    __syncthreads();
    const int start = blockIdx.x * ipb;
    const int end = (start + ipb < n) ? start + ipb : n;
    for (int i = start + tid; i < end; i += 256) {
        int k = keys[i];
        int p = atomicAdd(&cur[k >> SH], 1);
        bucketed[p] = (vals[i] << SH) | (k & (BK - 1));
    }
}

// Pass B: per-bucket exact CSR, 1024 keys/bucket
__global__ __launch_bounds__(256) void sort_finalize(const int* __restrict__ bucketed,
                                                     const int* __restrict__ cscan,
                                                     int* __restrict__ csr,
                                                     int* __restrict__ offs,
                                                     int* __restrict__ counts,
                                                     int n, int B, int nkeys) {
    __shared__ int h[BK];
    __shared__ int s[256];
    const int t = threadIdx.x;
    const int b = blockIdx.x;
    const int bstart = cscan[b * NBLK];
    const int bend = (b + 1 < B) ? cscan[(b + 1) * NBLK] : n;

    for (int i = t; i < BK; i += 256) h[i] = 0;
    __syncthreads();
    for (int i = bstart + t; i < bend; i += 256)
        atomicAdd(&h[bucketed[i] & (BK - 1)], 1);
    __syncthreads();
    const int c0 = h[t * 4], c1 = h[t * 4 + 1], c2 = h[t * 4 + 2], c3 = h[t * 4 + 3];
    const int tsum = c0 + c1 + c2 + c3;
    s[t] = tsum;
    __syncthreads();
    for (int o = 1; o < 256; o <<= 1) {
        int x = (t >= o) ? s[t - o] : 0;
        __syncthreads();
        s[t] += x;
        __syncthreads();
    }
    const int e0 = s[t] - tsum;
    const int e1 = e0 + c0, e2 = e1 + c1, e3 = e2 + c2;
    const int keyb = b * BK + t * 4;
    if (keyb + 0 < nkeys) { offs[keyb + 0] = bstart + e0; counts[keyb + 0] = c0; }
    if (keyb + 1 < nkeys) { offs[keyb + 1] = bstart + e1; counts[keyb + 1] = c1; }
    if (keyb + 2 < nkeys) { offs[keyb + 2] = bstart + e2; counts[keyb + 2] = c2; }
    if (keyb + 3 < nkeys) { offs[keyb + 3] = bstart + e3; counts[keyb + 3] = c3; }
    h[t * 4 + 0] = bstart + e0;
    h[t * 4 + 1] = bstart + e1;
    h[t * 4 + 2] = bstart + e2;
    h[t * 4 + 3] = bstart + e3;
    __syncthreads();
    for (int i = bstart + t; i < bend; i += 256) {
        int e = bucketed[i];
        int p = atomicAdd(&h[e & (BK - 1)], 1);
        csr[p] = e >> SH;
    }
}

// ---------------------------------------------------------------------------
// Gather fp16 src: wave/row, 4 row-fetches in flight, 16 lanes x half4.
// ---------------------------------------------------------------------------
__global__ __launch_bounds__(256) void gather_h4(const _Float16* __restrict__ src,
                                                 const int* __restrict__ csr,
                                                 const int* __restrict__ offs,
                                                 const int* __restrict__ counts,
                                                 float* __restrict__ dst, int nrows) {
    const int wave = (blockIdx.x * 256 + threadIdx.x) >> 6;
    const int lane = threadIdx.x & 63;
    if (wave >= nrows) return;
    const int group = lane >> 4, sub = lane & 15;
    const int start = offs[wave];
    const int end = start + counts[wave];

    float ax = 0.f, ay = 0.f, az = 0.f, aw = 0.f;
    float bx = 0.f, by = 0.f, bz = 0.f, bw = 0.f;
    int j = start + group;
    for (; j + 4 < end; j += 8) {
        int s0 = csr[j];
        int s1 = csr[j + 4];
        half4v a = *(const half4v*)&src[((size_t)s0 << 6) + sub * 4];
        half4v b = *(const half4v*)&src[((size_t)s1 << 6) + sub * 4];
        ax += (float)a.x; ay += (float)a.y; az += (float)a.z; aw += (float)a.w;
        bx += (float)b.x; by += (float)b.y; bz += (float)b.z; bw += (float)b.w;
    }
    if (j < end) {
        half4v a = *(const half4v*)&src[((size_t)csr[j] << 6) + sub * 4];
        ax += (float)a.x; ay += (float)a.y; az += (float)a.z; aw += (float)a.w;
    }
    ax += bx; ay += by; az += bz; aw += bw;
#pragma unroll
    for (int o = 16; o <= 32; o <<= 1) {
        ax += __shfl_xor(ax, o);
        ay += __shfl_xor(ay, o);
        az += __shfl_xor(az, o);
        aw += __shfl_xor(aw, o);
    }
    if (group == 0)
        *(float4*)&dst[((size_t)wave << 6) + sub * 4] = make_float4(ax, ay, az, aw);
}

__global__ __launch_bounds__(256) void gather_f4(const float* __restrict__ src,
                                                 const int* __restrict__ csr,
                                                 const int* __restrict__ offs,
                                                 const int* __restrict__ counts,
                                                 float* __restrict__ dst, int nrows) {
    const int wave = (blockIdx.x * 256 + threadIdx.x) >> 6;
    const int lane = threadIdx.x & 63;
    if (wave >= nrows) return;
    const int group = lane >> 4, sub = lane & 15;
    const int start = offs[wave];
    const int end = start + counts[wave];

    float ax = 0.f, ay = 0.f, az = 0.f, aw = 0.f;
    float bx = 0.f, by = 0.f, bz = 0.f, bw = 0.f;
    int j = start + group;
    for (; j + 4 < end; j += 8) {
        int s0 = csr[j];
        int s1 = csr[j + 4];
        float4 a = *(const float4*)&src[((size_t)s0 << 6) + sub * 4];
        float4 b = *(const float4*)&src[((size_t)s1 << 6) + sub * 4];
        ax += a.x; ay += a.y; az += a.z; aw += a.w;
        bx += b.x; by += b.y; bz += b.z; bw += b.w;
    }
    if (j < end) {
        float4 a = *(const float4*)&src[((size_t)csr[j] << 6) + sub * 4];
        ax += a.x; ay += a.y; az += a.z; aw += a.w;
    }
    ax += bx; ay += by; az += bz; aw += bw;
#pragma unroll
    for (int o = 16; o <= 32; o <<= 1) {
        ax += __shfl_xor(ax, o);
        ay += __shfl_xor(ay, o);
        az += __shfl_xor(az, o);
        aw += __shfl_xor(aw, o);
    }
    if (group == 0)
        *(float4*)&dst[((size_t)wave << 6) + sub * 4] = make_float4(ax, ay, az, aw);
}

static void build_csr(const int* keys, const int* vals, int NI, int nkeys,
                      int* cmat, int* cscan, int* bsums, int* bucketed,
                      int* csr, int* offs, int* counts, hipStream_t stream) {
    const int B = (nkeys + BK - 1) >> SH;
    const int L = B * NBLK;
    const int ipb = (NI + NBLK - 1) / NBLK;
    const int nsb = (L + 1023) / 1024;
    sort_hist<<<NBLK, 256, 0, stream>>>(keys, cmat, NI, B, ipb);
    scan1<<<nsb, 256, 0, stream>>>(cmat, cscan, bsums, L);
    scan23<<<(L + 255) / 256, 256, 0, stream>>>(cscan, bsums, L, nsb);
    sort_scatter<<<NBLK, 256, 0, stream>>>(keys, vals, cscan, bucketed, NI, B, ipb);
    sort_finalize<<<B, 256, 0, stream>>>(bucketed, cscan, csr, offs, counts, NI, B, nkeys);
}

extern "C" void kernel_launch(void* const* d_in, const int* in_sizes, int n_in,
                              void* d_out, int out_size, void* d_ws, size_t ws_size,
                              hipStream_t stream) {
    const float* node  = (const float*)d_in[0];
    const float* hedge = (const float*)d_in[1];
    const float* W_nn  = (const float*)d_in[2];
    const float* W_nh  = (const float*)d_in[3];
    const float* W_hh  = (const float*)d_in[4];
    const float* W_hn  = (const float*)d_in[5];
    const int* node_idx  = (const int*)d_in[6];
    const int* hedge_idx = (const int*)d_in[7];

    const int N  = in_sizes[0] / D;   // 200,000
    const int E  = in_sizes[1] / D;   // 100,000
    const int NI = in_sizes[6];       // 1,600,000
    const int maxNE = (N > E) ? N : E;
    const int maxB = (maxNE + BK - 1) >> SH;

    float* out_node  = (float*)d_out;                  // [N,64]
    float* out_hedge = out_node + (size_t)N * D;       // [E,64] (scratch: hproj fp16, g1 f32)

    float*     nbuf     = (float*)d_ws;                // ngate / agg (f32)
    int*       bucketed = (int*)(nbuf + (size_t)N * D);
    int*       csr      = bucketed + NI;
    int*       cmat     = csr + NI;
    int*       cscan    = cmat + (size_t)maxB * NBLK;
    int*       offs     = cscan + (size_t)maxB * NBLK;
    int*       counts   = offs + maxNE;
    int*       bsums    = counts + maxNE;
    _Float16*  nodeh    = (_Float16*)(bsums + 256);

    const size_t need = (size_t)((char*)(nodeh + (size_t)N * D) - (char*)d_ws);
    const bool have_h = ws_size >= need;

    const int gbE = (E + 63) / 64;
    const int gbN = (N + 63) / 64;

    // ---------- phase 1: ngate = Mt-gather(hproj) ----------
    build_csr(node_idx, hedge_idx, NI, N, cmat, cscan, bsums, bucketed,
              csr, offs, counts, stream);
    // hproj = hedge @ W_nh (fp16 into out_hedge scratch)
    gemm64<0, 0, 1><<<gbE, 256, 0, stream>>>(hedge, W_nh, nullptr, nullptr,
                                             (_Float16*)out_hedge, E);
    gather_h4<<<(N + 3) / 4, 256, 0, stream>>>((const _Float16*)out_hedge, csr, offs,
                                               counts, nbuf, N);
    // new_node = tanh((node@W_nn)*ngate)  [+ fp16 copy if ws allows]
    if (have_h)
        gemm64<1, 1, 1><<<gbN, 256, 0, stream>>>(node, W_nn, nbuf, out_node, nodeh, N);
    else
        gemm64<1, 1, 0><<<gbN, 256, 0, stream>>>(node, W_nn, nbuf, out_node, nullptr, N);

    // ---------- phase 2: new_hedge = tanh((hedge@W_hh) * ((Mt-gather new_node)@W_hn)) ----------
    build_csr(hedge_idx, node_idx, NI, E, cmat, cscan, bsums, bucketed,
              csr, offs, counts, stream);
    if (have_h)
        gather_h4<<<(E + 3) / 4, 256, 0, stream>>>(nodeh, csr, offs, counts, nbuf, E);
    else
        gather_f4<<<(E + 3) / 4, 256, 0, stream>>>(out_node, csr, offs, counts, nbuf, E);
    // g1 = hedge @ W_hh -> out_hedge (f32)
    gemm64<0, 1, 0><<<gbE, 256, 0, stream>>>(hedge, W_hh, nullptr, out_hedge, nullptr, E);
    // new_hedge = tanh((agg @ W_hn) * g1), in place over g1
    gemm64<1, 1, 0><<<gbE, 256, 0, stream>>>(nbuf, W_hn, out_hedge, out_hedge, nullptr, E);
}

// Round 2
// 455.330 us; speedup vs baseline: 1.0521x; 1.0521x over previous
//
#include <hip/hip_runtime.h>

#define D 64
#define SH 10             // bucket = key >> SH; 1024 keys/bucket
#define BK 1024
#define NBLK 256          // blocks for sort passes A1/A2

typedef _Float16 half4v __attribute__((ext_vector_type(4)));
typedef _Float16 half8 __attribute__((ext_vector_type(8)));
typedef float f32x4 __attribute__((ext_vector_type(4)));

__device__ __forceinline__ float fast_tanh(float x) {
    float e = __expf(2.f * x);
    return 1.f - 2.f * __builtin_amdgcn_rcpf(e + 1.f);
}

// ---------------------------------------------------------------------------
// Split-fp16 MFMA GEMM: C[M,64] = A[M,64] @ W[64,64], fp32-accurate via
// A=Ah+Ar, W=Wh+Wr (fp16 hi + fp16 residual); C ≈ AhWh + ArWh + AhWr.
// GATE: C = tanh(C * gate) (gate may alias Cf — so NO restrict on gate/Cf).
// WF: fp32 out. WH: fp16 out.
// Block: 64 rows, 4 waves; wave rt -> rows rt*16..+15. W staged transposed.
// ---------------------------------------------------------------------------
template <int GATE, int WF, int WH>
__global__ __launch_bounds__(256) void gemm64(const float* __restrict__ A,
                                              const float* __restrict__ W,
                                              const float* gate,
                                              float* Cf,
                                              _Float16* Ch, int M) {
    __shared__ _Float16 Ahi[64 * 72];
    __shared__ _Float16 Are[64 * 72];
    __shared__ _Float16 Whi[64 * 72];   // transposed: [n][k]
    __shared__ _Float16 Wre[64 * 72];
    const int tid = threadIdx.x;
    const int base = blockIdx.x * 64;

#pragma unroll
    for (int i = 0; i < 4; ++i) {
        int idx4 = (tid + i * 256) * 4;          // 0..4095 step 4
        int r = idx4 >> 6, k = idx4 & 63;
        float4 va = make_float4(0.f, 0.f, 0.f, 0.f);
        if (base + r < M) va = *(const float4*)&A[(size_t)(base + r) * D + k];
        half4v hh, hr;
        hh.x = (_Float16)va.x; hr.x = (_Float16)(va.x - (float)hh.x);
        hh.y = (_Float16)va.y; hr.y = (_Float16)(va.y - (float)hh.y);
        hh.z = (_Float16)va.z; hr.z = (_Float16)(va.z - (float)hh.z);
        hh.w = (_Float16)va.w; hr.w = (_Float16)(va.w - (float)hh.w);
        *(half4v*)&Ahi[r * 72 + k] = hh;
        *(half4v*)&Are[r * 72 + k] = hr;
        // W row-major [k][n] -> staged transposed [n][k]
        int wk = idx4 >> 6, wn = idx4 & 63;
        float4 vw = *(const float4*)&W[idx4];
#pragma unroll
        for (int j = 0; j < 4; ++j) {
            float w = (&vw.x)[j];
            _Float16 h = (_Float16)w;
            Whi[(wn + j) * 72 + wk] = h;
            Wre[(wn + j) * 72 + wk] = (_Float16)(w - (float)h);
        }
    }
    __syncthreads();

    const int lane = tid & 63;
    const int rt = tid >> 6;          // wave's 16-row tile
    const int m = lane & 15;          // A row in tile / C col in tile
    const int q = lane >> 4;          // k-subchunk

    f32x4 acc[4] = {};
#pragma unroll
    for (int kc = 0; kc < 64; kc += 32) {
        half8 ah = *(const half8*)&Ahi[(rt * 16 + m) * 72 + kc + q * 8];
        half8 ar = *(const half8*)&Are[(rt * 16 + m) * 72 + kc + q * 8];
#pragma unroll
        for (int ct = 0; ct < 4; ++ct) {
            half8 bh = *(const half8*)&Whi[(ct * 16 + m) * 72 + kc + q * 8];
            half8 br = *(const half8*)&Wre[(ct * 16 + m) * 72 + kc + q * 8];
            acc[ct] = __builtin_amdgcn_mfma_f32_16x16x32_f16(ah, bh, acc[ct], 0, 0, 0);
            acc[ct] = __builtin_amdgcn_mfma_f32_16x16x32_f16(ar, bh, acc[ct], 0, 0, 0);
            acc[ct] = __builtin_amdgcn_mfma_f32_16x16x32_f16(ah, br, acc[ct], 0, 0, 0);
        }
    }

#pragma unroll
    for (int r_ = 0; r_ < 4; ++r_) {
        int row = base + rt * 16 + q * 4 + r_;
        if (row < M) {
#pragma unroll
            for (int ct = 0; ct < 4; ++ct) {
                size_t off = (size_t)row * D + ct * 16 + m;
                float v = acc[ct][r_];
                if (GATE) v = fast_tanh(v * gate[off]);
                if (WF) Cf[off] = v;
                if (WH) Ch[off] = (_Float16)v;
            }
        }
    }
}

// --------------------- zero-global-atomic counting sort ---------------------
__global__ __launch_bounds__(256) void sort_hist(const int* __restrict__ keys,
                                                 int* __restrict__ cmat,
                                                 int n, int B, int ipb) {
    __shared__ int h[256];
    const int tid = threadIdx.x;
    for (int i = tid; i < B; i += 256) h[i] = 0;
    __syncthreads();
    const int start = blockIdx.x * ipb;
    const int end = (start + ipb < n) ? start + ipb : n;
    for (int i = start + tid; i < end; i += 256)
        atomicAdd(&h[keys[i] >> SH], 1);
    __syncthreads();
    for (int b = tid; b < B; b += 256) cmat[b * NBLK + blockIdx.x] = h[b];
}

__global__ __launch_bounds__(256) void scan1(const int* __restrict__ src,
                                             int* __restrict__ dst,
                                             int* __restrict__ bsums, int n) {
    __shared__ int s[256];
    const int t = threadIdx.x;
    const int base = blockIdx.x * 1024 + t * 4;
    int v[4];
#pragma unroll
    for (int j = 0; j < 4; ++j) v[j] = (base + j < n) ? src[base + j] : 0;
    int tsum = v[0] + v[1] + v[2] + v[3];
    s[t] = tsum;
    __syncthreads();
    for (int o = 1; o < 256; o <<= 1) {
        int x = (t >= o) ? s[t - o] : 0;
        __syncthreads();
        s[t] += x;
        __syncthreads();
    }
    int run = s[t] - tsum;
    if (t == 255) bsums[blockIdx.x] = s[255];
#pragma unroll
    for (int j = 0; j < 4; ++j) {
        if (base + j < n) dst[base + j] = run;
        run += v[j];
    }
}

// Fused: exclusive-scan the per-block sums in LDS (redundantly per block),
// then add to this block's 256 elements. Replaces scan2+scan3.
__global__ __launch_bounds__(256) void scan23(int* __restrict__ a,
                                              const int* __restrict__ bsums,
                                              int n, int nb) {
    __shared__ int sb[256];
    const int t = threadIdx.x;
    int v = (t < nb) ? bsums[t] : 0;
    sb[t] = v;
    __syncthreads();
    for (int o = 1; o < 256; o <<= 1) {
        int x = (t >= o) ? sb[t - o] : 0;
        __syncthreads();
        sb[t] += x;
        __syncthreads();
    }
    int incl = sb[t];
    __syncthreads();
    sb[t] = incl - v;          // exclusive block prefix
    __syncthreads();
    int i = blockIdx.x * 256 + t;
    if (i < n) a[i] += sb[i >> 10];
}

__global__ __launch_bounds__(256) void sort_scatter(const int* __restrict__ keys,
                                                    const int* __restrict__ vals,
                                                    const int* __restrict__ cscan,
                                                    int* __restrict__ bucketed,
                                                    int n, int B, int ipb) {
    __shared__ int cur[256];
    const int tid = threadIdx.x;
    for (int i = tid; i < B; i += 256) cur[i] = cscan[i * NBLK + blockIdx.x];
    __syncthreads();
    const int start = blockIdx.x * ipb;
    const int end = (start + ipb < n) ? start + ipb : n;
    for (int i = start + tid; i < end; i += 256) {
        int k = keys[i];
        int p = atomicAdd(&cur[k >> SH], 1);
        bucketed[p] = (vals[i] << SH) | (k & (BK - 1));
    }
}

// Pass B: per-bucket exact CSR, 1024 keys/bucket
__global__ __launch_bounds__(256) void sort_finalize(const int* __restrict__ bucketed,
                                                     const int* __restrict__ cscan,
                                                     int* __restrict__ csr,
                                                     int* __restrict__ offs,
                                                     int* __restrict__ counts,
                                                     int n, int B, int nkeys) {
    __shared__ int h[BK];
    __shared__ int s[256];
    const int t = threadIdx.x;
    const int b = blockIdx.x;
    const int bstart = cscan[b * NBLK];
    const int bend = (b + 1 < B) ? cscan[(b + 1) * NBLK] : n;

    for (int i = t; i < BK; i += 256) h[i] = 0;
    __syncthreads();
    for (int i = bstart + t; i < bend; i += 256)
        atomicAdd(&h[bucketed[i] & (BK - 1)], 1);
    __syncthreads();
    const int c0 = h[t * 4], c1 = h[t * 4 + 1], c2 = h[t * 4 + 2], c3 = h[t * 4 + 3];
    const int tsum = c0 + c1 + c2 + c3;
    s[t] = tsum;
    __syncthreads();
    for (int o = 1; o < 256; o <<= 1) {
        int x = (t >= o) ? s[t - o] : 0;
        __syncthreads();
        s[t] += x;
        __syncthreads();
    }
    const int e0 = s[t] - tsum;
    const int e1 = e0 + c0, e2 = e1 + c1, e3 = e2 + c2;
    const int keyb = b * BK + t * 4;
    if (keyb + 0 < nkeys) { offs[keyb + 0] = bstart + e0; counts[keyb + 0] = c0; }
    if (keyb + 1 < nkeys) { offs[keyb + 1] = bstart + e1; counts[keyb + 1] = c1; }
    if (keyb + 2 < nkeys) { offs[keyb + 2] = bstart + e2; counts[keyb + 2] = c2; }
    if (keyb + 3 < nkeys) { offs[keyb + 3] = bstart + e3; counts[keyb + 3] = c3; }
    h[t * 4 + 0] = bstart + e0;
    h[t * 4 + 1] = bstart + e1;
    h[t * 4 + 2] = bstart + e2;
    h[t * 4 + 3] = bstart + e3;
    __syncthreads();
    for (int i = bstart + t; i < bend; i += 256) {
        int e = bucketed[i];
        int p = atomicAdd(&h[e & (BK - 1)], 1);
        csr[p] = e >> SH;
    }
}

// ---------------------------------------------------------------------------
// Gather, fp16 src: one 16-lane group per dst row (4 rows/wave, 16/block).
// Each lane owns 4 features; 4-deep unroll -> 4 independent row loads per
// step, csr entries contiguous -> broadcast loads. No cross-lane reduction.
// ---------------------------------------------------------------------------
__global__ __launch_bounds__(256) void gather_h4(const _Float16* __restrict__ src,
                                                 const int* __restrict__ csr,
                                                 const int* __restrict__ offs,
                                                 const int* __restrict__ counts,
                                                 float* __restrict__ dst, int nrows) {
    const int row = blockIdx.x * 16 + (threadIdx.x >> 4);
    const int sub = threadIdx.x & 15;
    if (row >= nrows) return;
    const int start = offs[row];
    const int end = start + counts[row];

    f32x4 a0 = {}, a1 = {}, a2 = {}, a3 = {};
    int j = start;
    for (; j + 3 < end; j += 4) {
        int c0 = csr[j], c1 = csr[j + 1], c2 = csr[j + 2], c3 = csr[j + 3];
        half4v v0 = *(const half4v*)&src[((size_t)c0 << 6) + sub * 4];
        half4v v1 = *(const half4v*)&src[((size_t)c1 << 6) + sub * 4];
        half4v v2 = *(const half4v*)&src[((size_t)c2 << 6) + sub * 4];
        half4v v3 = *(const half4v*)&src[((size_t)c3 << 6) + sub * 4];
        a0 += __builtin_convertvector(v0, f32x4);
        a1 += __builtin_convertvector(v1, f32x4);
        a2 += __builtin_convertvector(v2, f32x4);
        a3 += __builtin_convertvector(v3, f32x4);
    }
    for (; j < end; ++j) {
        int c = csr[j];
        half4v v = *(const half4v*)&src[((size_t)c << 6) + sub * 4];
        a0 += __builtin_convertvector(v, f32x4);
    }
    f32x4 r = (a0 + a1) + (a2 + a3);
    __builtin_nontemporal_store(r, (f32x4*)&dst[((size_t)row << 6) + sub * 4]);
}

__global__ __launch_bounds__(256) void gather_f4(const float* __restrict__ src,
                                                 const int* __restrict__ csr,
                                                 const int* __restrict__ offs,
                                                 const int* __restrict__ counts,
                                                 float* __restrict__ dst, int nrows) {
    const int row = blockIdx.x * 16 + (threadIdx.x >> 4);
    const int sub = threadIdx.x & 15;
    if (row >= nrows) return;
    const int start = offs[row];
    const int end = start + counts[row];

    f32x4 a0 = {}, a1 = {}, a2 = {}, a3 = {};
    int j = start;
    for (; j + 3 < end; j += 4) {
        int c0 = csr[j], c1 = csr[j + 1], c2 = csr[j + 2], c3 = csr[j + 3];
        f32x4 v0 = *(const f32x4*)&src[((size_t)c0 << 6) + sub * 4];
        f32x4 v1 = *(const f32x4*)&src[((size_t)c1 << 6) + sub * 4];
        f32x4 v2 = *(const f32x4*)&src[((size_t)c2 << 6) + sub * 4];
        f32x4 v3 = *(const f32x4*)&src[((size_t)c3 << 6) + sub * 4];
        a0 += v0; a1 += v1; a2 += v2; a3 += v3;
    }
    for (; j < end; ++j) {
        int c = csr[j];
        a0 += *(const f32x4*)&src[((size_t)c << 6) + sub * 4];
    }
    f32x4 r = (a0 + a1) + (a2 + a3);
    __builtin_nontemporal_store(r, (f32x4*)&dst[((size_t)row << 6) + sub * 4]);
}

static void build_csr(const int* keys, const int* vals, int NI, int nkeys,
                      int* cmat, int* cscan, int* bsums, int* bucketed,
                      int* csr, int* offs, int* counts, hipStream_t stream) {
    const int B = (nkeys + BK - 1) >> SH;
    const int L = B * NBLK;
    const int ipb = (NI + NBLK - 1) / NBLK;
    const int nsb = (L + 1023) / 1024;
    sort_hist<<<NBLK, 256, 0, stream>>>(keys, cmat, NI, B, ipb);
    scan1<<<nsb, 256, 0, stream>>>(cmat, cscan, bsums, L);
    scan23<<<(L + 255) / 256, 256, 0, stream>>>(cscan, bsums, L, nsb);
    sort_scatter<<<NBLK, 256, 0, stream>>>(keys, vals, cscan, bucketed, NI, B, ipb);
    sort_finalize<<<B, 256, 0, stream>>>(bucketed, cscan, csr, offs, counts, NI, B, nkeys);
}

extern "C" void kernel_launch(void* const* d_in, const int* in_sizes, int n_in,
                              void* d_out, int out_size, void* d_ws, size_t ws_size,
                              hipStream_t stream) {
    const float* node  = (const float*)d_in[0];
    const float* hedge = (const float*)d_in[1];
    const float* W_nn  = (const float*)d_in[2];
    const float* W_nh  = (const float*)d_in[3];
    const float* W_hh  = (const float*)d_in[4];
    const float* W_hn  = (const float*)d_in[5];
    const int* node_idx  = (const int*)d_in[6];
    const int* hedge_idx = (const int*)d_in[7];

    const int N  = in_sizes[0] / D;   // 200,000
    const int E  = in_sizes[1] / D;   // 100,000
    const int NI = in_sizes[6];       // 1,600,000
    const int maxNE = (N > E) ? N : E;
    const int maxB = (maxNE + BK - 1) >> SH;

    float* out_node  = (float*)d_out;                  // [N,64]
    float* out_hedge = out_node + (size_t)N * D;       // [E,64] (scratch: hproj fp16, g1 f32)

    float*     nbuf     = (float*)d_ws;                // ngate / agg (f32)
    int*       bucketed = (int*)(nbuf + (size_t)N * D);
    int*       csr      = bucketed + NI;
    int*       cmat     = csr + NI;
    int*       cscan    = cmat + (size_t)maxB * NBLK;
    int*       offs     = cscan + (size_t)maxB * NBLK;
    int*       counts   = offs + maxNE;
    int*       bsums    = counts + maxNE;
    _Float16*  nodeh    = (_Float16*)(bsums + 256);

    const size_t need = (size_t)((char*)(nodeh + (size_t)N * D) - (char*)d_ws);
    const bool have_h = ws_size >= need;

    const int gbE = (E + 63) / 64;
    const int gbN = (N + 63) / 64;

    // ---------- phase 1: ngate = Mt-gather(hproj) ----------
    build_csr(node_idx, hedge_idx, NI, N, cmat, cscan, bsums, bucketed,
              csr, offs, counts, stream);
    // hproj = hedge @ W_nh (fp16 into out_hedge scratch)
    gemm64<0, 0, 1><<<gbE, 256, 0, stream>>>(hedge, W_nh, nullptr, nullptr,
                                             (_Float16*)out_hedge, E);
    gather_h4<<<(N + 15) / 16, 256, 0, stream>>>((const _Float16*)out_hedge, csr, offs,
                                                 counts, nbuf, N);
    // new_node = tanh((node@W_nn)*ngate)  [+ fp16 copy if ws allows]
    if (have_h)
        gemm64<1, 1, 1><<<gbN, 256, 0, stream>>>(node, W_nn, nbuf, out_node, nodeh, N);
    else
        gemm64<1, 1, 0><<<gbN, 256, 0, stream>>>(node, W_nn, nbuf, out_node, nullptr, N);

    // ---------- phase 2: new_hedge = tanh((hedge@W_hh) * ((Mt-gather new_node)@W_hn)) ----------
    build_csr(hedge_idx, node_idx, NI, E, cmat, cscan, bsums, bucketed,
              csr, offs, counts, stream);
    if (have_h)
        gather_h4<<<(E + 15) / 16, 256, 0, stream>>>(nodeh, csr, offs, counts, nbuf, E);
    else
        gather_f4<<<(E + 15) / 16, 256, 0, stream>>>(out_node, csr, offs, counts, nbuf, E);
    // g1 = hedge @ W_hh -> out_hedge (f32)
    gemm64<0, 1, 0><<<gbE, 256, 0, stream>>>(hedge, W_hh, nullptr, out_hedge, nullptr, E);
    // new_hedge = tanh((agg @ W_hn) * g1), in place over g1
    gemm64<1, 1, 0><<<gbE, 256, 0, stream>>>(nbuf, W_hn, out_hedge, out_hedge, nullptr, E);
}

// Round 3
// 441.446 us; speedup vs baseline: 1.0852x; 1.0315x over previous
//
#include <hip/hip_runtime.h>

#define D 64
#define SH 10             // bucket = key >> SH; 1024 keys/bucket
#define BK 1024
#define NBLK 256          // blocks for sort passes A1/A2

typedef _Float16 half4v __attribute__((ext_vector_type(4)));
typedef _Float16 half8 __attribute__((ext_vector_type(8)));
typedef float f32x4 __attribute__((ext_vector_type(4)));

__device__ __forceinline__ float fast_tanh(float x) {
    float e = __expf(2.f * x);
    return 1.f - 2.f * __builtin_amdgcn_rcpf(e + 1.f);
}

// Split two float4 (8 consecutive k) into fp16 hi + fp16 residual half8s.
__device__ __forceinline__ void split8(const float4& x, const float4& y,
                                       half8& h, half8& r) {
    const float* f0 = &x.x;
    const float* f1 = &y.x;
#pragma unroll
    for (int j = 0; j < 4; ++j) {
        _Float16 a = (_Float16)f0[j];
        h[j] = a; r[j] = (_Float16)(f0[j] - (float)a);
        _Float16 b = (_Float16)f1[j];
        h[j + 4] = b; r[j + 4] = (_Float16)(f1[j] - (float)b);
    }
}

// Stage one 64x64 W (row-major [k][n]) into LDS as transposed [n][k] fp16
// hi (at lb) + residual (at lb+8192), XOR-swizzled: byte ^= (n&7)<<4.
// Thread: n = tid&63 (coalesced 256B global reads per instr), kg = tid>>6.
__device__ __forceinline__ void stage_w(const float* __restrict__ W, char* lb,
                                        int n, int kg, int b0, int b1) {
    float wf[16];
#pragma unroll
    for (int j = 0; j < 16; ++j) wf[j] = W[(kg * 16 + j) * D + n];
    half8 h0, h1, r0, r1;
#pragma unroll
    for (int j = 0; j < 8; ++j) {
        _Float16 a = (_Float16)wf[j];
        h0[j] = a; r0[j] = (_Float16)(wf[j] - (float)a);
        _Float16 b = (_Float16)wf[j + 8];
        h1[j] = b; r1[j] = (_Float16)(wf[j + 8] - (float)b);
    }
    *(half8*)(lb + b0) = h0;
    *(half8*)(lb + b1) = h1;
    *(half8*)(lb + 8192 + b0) = r0;
    *(half8*)(lb + 8192 + b1) = r1;
}

// ---------------------------------------------------------------------------
// Split-fp16 MFMA GEMM: C[M,64] = A[M,64] @ W[64,64], fp32-accurate via
// A=Ah+Ar, W=Wh+Wr; C ≈ AhWh + ArWh + AhWr.
// A loaded DIRECT to registers (lane (m,q) owns row rt*16+m, k=q*8..+8 per
// 32-k slab) — no A LDS, no A barrier. W staged in 16KB swizzled LDS.
// Gate prefetched at block entry. GATE: C = tanh(C*gate). WF f32 / WH fp16.
// ---------------------------------------------------------------------------
template <int GATE, int WF, int WH>
__global__ __launch_bounds__(256) void gemm64(const float* __restrict__ A,
                                              const float* __restrict__ W,
                                              const float* __restrict__ gate,
                                              float* __restrict__ Cf,
                                              _Float16* __restrict__ Ch, int M) {
    __shared__ _Float16 Wlds[8192];   // 16KB: hi [0,8K), re [8K,16K)
    const int tid = threadIdx.x;
    const int base = blockIdx.x * 64;
    const int lane = tid & 63;
    const int rt = tid >> 6;
    const int m = lane & 15;
    const int q = lane >> 4;

    // ---- A direct loads ----
    const int arow = base + rt * 16 + m;
    const bool aok = arow < M;
    const float* ap = A + (size_t)(aok ? arow : 0) * D + q * 8;
    const float4 z4 = make_float4(0.f, 0.f, 0.f, 0.f);
    float4 a0 = aok ? *(const float4*)(ap)      : z4;
    float4 a1 = aok ? *(const float4*)(ap + 4)  : z4;
    float4 a2 = aok ? *(const float4*)(ap + 32) : z4;
    float4 a3 = aok ? *(const float4*)(ap + 36) : z4;

    // ---- gate prefetch (addresses known at entry; overlaps everything) ----
    float gv[16];
    if (GATE) {
#pragma unroll
        for (int r_ = 0; r_ < 4; ++r_) {
            int row2 = base + rt * 16 + q * 4 + r_;
            if (row2 < M) {
#pragma unroll
                for (int ct = 0; ct < 4; ++ct)
                    gv[r_ * 4 + ct] = gate[(size_t)row2 * D + ct * 16 + m];
            }
        }
    }

    // ---- W stage ----
    {
        const int n = tid & 63, kg = tid >> 6;
        const int b0 = (n * 128 + kg * 32) ^ ((n & 7) << 4);
        const int b1 = (n * 128 + kg * 32 + 16) ^ ((n & 7) << 4);
        stage_w(W, (char*)Wlds, n, kg, b0, b1);
    }

    half8 ah0, ar0, ah1, ar1;
    split8(a0, a1, ah0, ar0);
    split8(a2, a3, ah1, ar1);

    __syncthreads();

    f32x4 acc[4] = {};
    const char* lb = (const char*)Wlds;
#pragma unroll
    for (int kc2 = 0; kc2 < 2; ++kc2) {
        half8 ah = kc2 ? ah1 : ah0;
        half8 ar = kc2 ? ar1 : ar0;
#pragma unroll
        for (int ct = 0; ct < 4; ++ct) {
            int n2 = ct * 16 + m;
            int boff = (n2 * 128 + kc2 * 64 + q * 16) ^ ((n2 & 7) << 4);
            half8 bh = *(const half8*)(lb + boff);
            half8 br = *(const half8*)(lb + 8192 + boff);
            acc[ct] = __builtin_amdgcn_mfma_f32_16x16x32_f16(ah, bh, acc[ct], 0, 0, 0);
            acc[ct] = __builtin_amdgcn_mfma_f32_16x16x32_f16(ar, bh, acc[ct], 0, 0, 0);
            acc[ct] = __builtin_amdgcn_mfma_f32_16x16x32_f16(ah, br, acc[ct], 0, 0, 0);
        }
    }

#pragma unroll
    for (int r_ = 0; r_ < 4; ++r_) {
        int row = base + rt * 16 + q * 4 + r_;
        if (row < M) {
#pragma unroll
            for (int ct = 0; ct < 4; ++ct) {
                size_t off = (size_t)row * D + ct * 16 + m;
                float v = acc[ct][r_];
                if (GATE) v = fast_tanh(v * gv[r_ * 4 + ct]);
                if (WF) Cf[off] = v;
                if (WH) Ch[off] = (_Float16)v;
            }
        }
    }
}

// ---------------------------------------------------------------------------
// Fused phase-2 tail: Cf = tanh((A1@W1) * (A2@W2)) — kills the 25.6MB f32
// intermediate round-trip and one dispatch. 32KB LDS (two staged W's).
// ---------------------------------------------------------------------------
__global__ __launch_bounds__(256) void gemm64_fused(const float* __restrict__ A1,
                                                    const float* __restrict__ W1,
                                                    const float* __restrict__ A2,
                                                    const float* __restrict__ W2,
                                                    float* __restrict__ Cf, int M) {
    __shared__ _Float16 Wlds[16384];  // 32KB: W1hi,W1re,W2hi,W2re (8KB each)
    const int tid = threadIdx.x;
    const int base = blockIdx.x * 64;
    const int lane = tid & 63;
    const int rt = tid >> 6;
    const int m = lane & 15;
    const int q = lane >> 4;

    const int arow = base + rt * 16 + m;
    const bool aok = arow < M;
    const size_t aoff = (size_t)(aok ? arow : 0) * D + q * 8;
    const float4 z4 = make_float4(0.f, 0.f, 0.f, 0.f);
    float4 p0 = aok ? *(const float4*)(A1 + aoff)      : z4;
    float4 p1 = aok ? *(const float4*)(A1 + aoff + 4)  : z4;
    float4 p2 = aok ? *(const float4*)(A1 + aoff + 32) : z4;
    float4 p3 = aok ? *(const float4*)(A1 + aoff + 36) : z4;
    float4 s0 = aok ? *(const float4*)(A2 + aoff)      : z4;
    float4 s1 = aok ? *(const float4*)(A2 + aoff + 4)  : z4;
    float4 s2 = aok ? *(const float4*)(A2 + aoff + 32) : z4;
    float4 s3 = aok ? *(const float4*)(A2 + aoff + 36) : z4;

    char* lb = (char*)Wlds;
    const int n = tid & 63, kg = tid >> 6;
    const int b0 = (n * 128 + kg * 32) ^ ((n & 7) << 4);
    const int b1 = (n * 128 + kg * 32 + 16) ^ ((n & 7) << 4);
    stage_w(W1, lb, n, kg, b0, b1);
    stage_w(W2, lb + 16384, n, kg, b0, b1);

    half8 pah0, par0, pah1, par1, sah0, sar0, sah1, sar1;
    split8(p0, p1, pah0, par0);
    split8(p2, p3, pah1, par1);
    split8(s0, s1, sah0, sar0);
    split8(s2, s3, sah1, sar1);

    __syncthreads();

    f32x4 acc1[4] = {}, acc2[4] = {};
#pragma unroll
    for (int kc2 = 0; kc2 < 2; ++kc2) {
        half8 pah = kc2 ? pah1 : pah0;
        half8 par = kc2 ? par1 : par0;
        half8 sah = kc2 ? sah1 : sah0;
        half8 sar = kc2 ? sar1 : sar0;
#pragma unroll
        for (int ct = 0; ct < 4; ++ct) {
            int n2 = ct * 16 + m;
            int boff = (n2 * 128 + kc2 * 64 + q * 16) ^ ((n2 & 7) << 4);
            half8 bh = *(const half8*)(lb + boff);
            half8 br = *(const half8*)(lb + 8192 + boff);
            acc1[ct] = __builtin_amdgcn_mfma_f32_16x16x32_f16(pah, bh, acc1[ct], 0, 0, 0);
            acc1[ct] = __builtin_amdgcn_mfma_f32_16x16x32_f16(par, bh, acc1[ct], 0, 0, 0);
            acc1[ct] = __builtin_amdgcn_mfma_f32_16x16x32_f16(pah, br, acc1[ct], 0, 0, 0);
            half8 ch = *(const half8*)(lb + 16384 + boff);
            half8 cr = *(const half8*)(lb + 24576 + boff);
            acc2[ct] = __builtin_amdgcn_mfma_f32_16x16x32_f16(sah, ch, acc2[ct], 0, 0, 0);
            acc2[ct] = __builtin_amdgcn_mfma_f32_16x16x32_f16(sar, ch, acc2[ct], 0, 0, 0);
            acc2[ct] = __builtin_amdgcn_mfma_f32_16x16x32_f16(sah, cr, acc2[ct], 0, 0, 0);
        }
    }

#pragma unroll
    for (int r_ = 0; r_ < 4; ++r_) {
        int row = base + rt * 16 + q * 4 + r_;
        if (row < M) {
#pragma unroll
            for (int ct = 0; ct < 4; ++ct) {
                size_t off = (size_t)row * D + ct * 16 + m;
                Cf[off] = fast_tanh(acc1[ct][r_] * acc2[ct][r_]);
            }
        }
    }
}

// --------------------- zero-global-atomic counting sort ---------------------
__global__ __launch_bounds__(256) void sort_hist(const int* __restrict__ keys,
                                                 int* __restrict__ cmat,
                                                 int n, int B, int ipb) {
    __shared__ int h[256];
    const int tid = threadIdx.x;
    for (int i = tid; i < B; i += 256) h[i] = 0;
    __syncthreads();
    const int start = blockIdx.x * ipb;
    const int end = (start + ipb < n) ? start + ipb : n;
    for (int i = start + tid; i < end; i += 256)
        atomicAdd(&h[keys[i] >> SH], 1);
    __syncthreads();
    for (int b = tid; b < B; b += 256) cmat[b * NBLK + blockIdx.x] = h[b];
}

__global__ __launch_bounds__(256) void scan1(const int* __restrict__ src,
                                             int* __restrict__ dst,
                                             int* __restrict__ bsums, int n) {
    __shared__ int s[256];
    const int t = threadIdx.x;
    const int base = blockIdx.x * 1024 + t * 4;
    int v[4];
#pragma unroll
    for (int j = 0; j < 4; ++j) v[j] = (base + j < n) ? src[base + j] : 0;
    int tsum = v[0] + v[1] + v[2] + v[3];
    s[t] = tsum;
    __syncthreads();
    for (int o = 1; o < 256; o <<= 1) {
        int x = (t >= o) ? s[t - o] : 0;
        __syncthreads();
        s[t] += x;
        __syncthreads();
    }
    int run = s[t] - tsum;
    if (t == 255) bsums[blockIdx.x] = s[255];
#pragma unroll
    for (int j = 0; j < 4; ++j) {
        if (base + j < n) dst[base + j] = run;
        run += v[j];
    }
}

// Fused: exclusive-scan the per-block sums in LDS (redundantly per block),
// then add to this block's 256 elements. Replaces scan2+scan3.
__global__ __launch_bounds__(256) void scan23(int* __restrict__ a,
                                              const int* __restrict__ bsums,
                                              int n, int nb) {
    __shared__ int sb[256];
    const int t = threadIdx.x;
    int v = (t < nb) ? bsums[t] : 0;
    sb[t] = v;
    __syncthreads();
    for (int o = 1; o < 256; o <<= 1) {
        int x = (t >= o) ? sb[t - o] : 0;
        __syncthreads();
        sb[t] += x;
        __syncthreads();
    }
    int incl = sb[t];
    __syncthreads();
    sb[t] = incl - v;          // exclusive block prefix
    __syncthreads();
    int i = blockIdx.x * 256 + t;
    if (i < n) a[i] += sb[i >> 10];
}

__global__ __launch_bounds__(256) void sort_scatter(const int* __restrict__ keys,
                                                    const int* __restrict__ vals,
                                                    const int* __restrict__ cscan,
                                                    int* __restrict__ bucketed,
                                                    int n, int B, int ipb) {
    __shared__ int cur[256];
    const int tid = threadIdx.x;
    for (int i = tid; i < B; i += 256) cur[i] = cscan[i * NBLK + blockIdx.x];
    __syncthreads();
    const int start = blockIdx.x * ipb;
    const int end = (start + ipb < n) ? start + ipb : n;
    for (int i = start + tid; i < end; i += 256) {
        int k = keys[i];
        int p = atomicAdd(&cur[k >> SH], 1);
        bucketed[p] = (vals[i] << SH) | (k & (BK - 1));
    }
}

// Pass B: per-bucket exact CSR, 1024 keys/bucket
__global__ __launch_bounds__(256) void sort_finalize(const int* __restrict__ bucketed,
                                                     const int* __restrict__ cscan,
                                                     int* __restrict__ csr,
                                                     int* __restrict__ offs,
                                                     int* __restrict__ counts,
                                                     int n, int B, int nkeys) {
    __shared__ int h[BK];
    __shared__ int s[256];
    const int t = threadIdx.x;
    const int b = blockIdx.x;
    const int bstart = cscan[b * NBLK];
    const int bend = (b + 1 < B) ? cscan[(b + 1) * NBLK] : n;

    for (int i = t; i < BK; i += 256) h[i] = 0;
    __syncthreads();
    for (int i = bstart + t; i < bend; i += 256)
        atomicAdd(&h[bucketed[i] & (BK - 1)], 1);
    __syncthreads();
    const int c0 = h[t * 4], c1 = h[t * 4 + 1], c2 = h[t * 4 + 2], c3 = h[t * 4 + 3];
    const int tsum = c0 + c1 + c2 + c3;
    s[t] = tsum;
    __syncthreads();
    for (int o = 1; o < 256; o <<= 1) {
        int x = (t >= o) ? s[t - o] : 0;
        __syncthreads();
        s[t] += x;
        __syncthreads();
    }
    const int e0 = s[t] - tsum;
    const int e1 = e0 + c0, e2 = e1 + c1, e3 = e2 + c2;
    const int keyb = b * BK + t * 4;
    if (keyb + 0 < nkeys) { offs[keyb + 0] = bstart + e0; counts[keyb + 0] = c0; }
    if (keyb + 1 < nkeys) { offs[keyb + 1] = bstart + e1; counts[keyb + 1] = c1; }
    if (keyb + 2 < nkeys) { offs[keyb + 2] = bstart + e2; counts[keyb + 2] = c2; }
    if (keyb + 3 < nkeys) { offs[keyb + 3] = bstart + e3; counts[keyb + 3] = c3; }
    h[t * 4 + 0] = bstart + e0;
    h[t * 4 + 1] = bstart + e1;
    h[t * 4 + 2] = bstart + e2;
    h[t * 4 + 3] = bstart + e3;
    __syncthreads();
    for (int i = bstart + t; i < bend; i += 256) {
        int e = bucketed[i];
        int p = atomicAdd(&h[e & (BK - 1)], 1);
        csr[p] = e >> SH;
    }
}

// ---------------------------------------------------------------------------
// Gather, fp16 src: one 16-lane group per dst row (4 rows/wave, 16/block).
// ---------------------------------------------------------------------------
__global__ __launch_bounds__(256) void gather_h4(const _Float16* __restrict__ src,
                                                 const int* __restrict__ csr,
                                                 const int* __restrict__ offs,
                                                 const int* __restrict__ counts,
                                                 float* __restrict__ dst, int nrows) {
    const int row = blockIdx.x * 16 + (threadIdx.x >> 4);
    const int sub = threadIdx.x & 15;
    if (row >= nrows) return;
    const int start = offs[row];
    const int end = start + counts[row];

    f32x4 a0 = {}, a1 = {}, a2 = {}, a3 = {};
    int j = start;
    for (; j + 3 < end; j += 4) {
        int c0 = csr[j], c1 = csr[j + 1], c2 = csr[j + 2], c3 = csr[j + 3];
        half4v v0 = *(const half4v*)&src[((size_t)c0 << 6) + sub * 4];
        half4v v1 = *(const half4v*)&src[((size_t)c1 << 6) + sub * 4];
        half4v v2 = *(const half4v*)&src[((size_t)c2 << 6) + sub * 4];
        half4v v3 = *(const half4v*)&src[((size_t)c3 << 6) + sub * 4];
        a0 += __builtin_convertvector(v0, f32x4);
        a1 += __builtin_convertvector(v1, f32x4);
        a2 += __builtin_convertvector(v2, f32x4);
        a3 += __builtin_convertvector(v3, f32x4);
    }
    for (; j < end; ++j) {
        int c = csr[j];
        half4v v = *(const half4v*)&src[((size_t)c << 6) + sub * 4];
        a0 += __builtin_convertvector(v, f32x4);
    }
    f32x4 r = (a0 + a1) + (a2 + a3);
    __builtin_nontemporal_store(r, (f32x4*)&dst[((size_t)row << 6) + sub * 4]);
}

__global__ __launch_bounds__(256) void gather_f4(const float* __restrict__ src,
                                                 const int* __restrict__ csr,
                                                 const int* __restrict__ offs,
                                                 const int* __restrict__ counts,
                                                 float* __restrict__ dst, int nrows) {
    const int row = blockIdx.x * 16 + (threadIdx.x >> 4);
    const int sub = threadIdx.x & 15;
    if (row >= nrows) return;
    const int start = offs[row];
    const int end = start + counts[row];

    f32x4 a0 = {}, a1 = {}, a2 = {}, a3 = {};
    int j = start;
    for (; j + 3 < end; j += 4) {
        int c0 = csr[j], c1 = csr[j + 1], c2 = csr[j + 2], c3 = csr[j + 3];
        f32x4 v0 = *(const f32x4*)&src[((size_t)c0 << 6) + sub * 4];
        f32x4 v1 = *(const f32x4*)&src[((size_t)c1 << 6) + sub * 4];
        f32x4 v2 = *(const f32x4*)&src[((size_t)c2 << 6) + sub * 4];
        f32x4 v3 = *(const f32x4*)&src[((size_t)c3 << 6) + sub * 4];
        a0 += v0; a1 += v1; a2 += v2; a3 += v3;
    }
    for (; j < end; ++j) {
        int c = csr[j];
        a0 += *(const f32x4*)&src[((size_t)c << 6) + sub * 4];
    }
    f32x4 r = (a0 + a1) + (a2 + a3);
    __builtin_nontemporal_store(r, (f32x4*)&dst[((size_t)row << 6) + sub * 4]);
}

static void build_csr(const int* keys, const int* vals, int NI, int nkeys,
                      int* cmat, int* cscan, int* bsums, int* bucketed,
                      int* csr, int* offs, int* counts, hipStream_t stream) {
    const int B = (nkeys + BK - 1) >> SH;
    const int L = B * NBLK;
    const int ipb = (NI + NBLK - 1) / NBLK;
    const int nsb = (L + 1023) / 1024;
    sort_hist<<<NBLK, 256, 0, stream>>>(keys, cmat, NI, B, ipb);
    scan1<<<nsb, 256, 0, stream>>>(cmat, cscan, bsums, L);
    scan23<<<(L + 255) / 256, 256, 0, stream>>>(cscan, bsums, L, nsb);
    sort_scatter<<<NBLK, 256, 0, stream>>>(keys, vals, cscan, bucketed, NI, B, ipb);
    sort_finalize<<<B, 256, 0, stream>>>(bucketed, cscan, csr, offs, counts, NI, B, nkeys);
}

extern "C" void kernel_launch(void* const* d_in, const int* in_sizes, int n_in,
                              void* d_out, int out_size, void* d_ws, size_t ws_size,
                              hipStream_t stream) {
    const float* node  = (const float*)d_in[0];
    const float* hedge = (const float*)d_in[1];
    const float* W_nn  = (const float*)d_in[2];
    const float* W_nh  = (const float*)d_in[3];
    const float* W_hh  = (const float*)d_in[4];
    const float* W_hn  = (const float*)d_in[5];
    const int* node_idx  = (const int*)d_in[6];
    const int* hedge_idx = (const int*)d_in[7];

    const int N  = in_sizes[0] / D;   // 200,000
    const int E  = in_sizes[1] / D;   // 100,000
    const int NI = in_sizes[6];       // 1,600,000
    const int maxNE = (N > E) ? N : E;
    const int maxB = (maxNE + BK - 1) >> SH;

    float* out_node  = (float*)d_out;                  // [N,64]
    float* out_hedge = out_node + (size_t)N * D;       // [E,64] (scratch: hproj fp16)

    float*     nbuf     = (float*)d_ws;                // ngate / agg (f32)
    int*       bucketed = (int*)(nbuf + (size_t)N * D);
    int*       csr      = bucketed + NI;
    int*       cmat     = csr + NI;
    int*       cscan    = cmat + (size_t)maxB * NBLK;
    int*       offs     = cscan + (size_t)maxB * NBLK;
    int*       counts   = offs + maxNE;
    int*       bsums    = counts + maxNE;
    _Float16*  nodeh    = (_Float16*)(bsums + 256);

    const size_t need = (size_t)((char*)(nodeh + (size_t)N * D) - (char*)d_ws);
    const bool have_h = ws_size >= need;

    const int gbE = (E + 63) / 64;
    const int gbN = (N + 63) / 64;

    // ---------- phase 1: ngate = Mt-gather(hproj) ----------
    build_csr(node_idx, hedge_idx, NI, N, cmat, cscan, bsums, bucketed,
              csr, offs, counts, stream);
    // hproj = hedge @ W_nh (fp16 into out_hedge scratch)
    gemm64<0, 0, 1><<<gbE, 256, 0, stream>>>(hedge, W_nh, nullptr, nullptr,
                                             (_Float16*)out_hedge, E);
    gather_h4<<<(N + 15) / 16, 256, 0, stream>>>((const _Float16*)out_hedge, csr, offs,
                                                 counts, nbuf, N);
    // new_node = tanh((node@W_nn)*ngate)  [+ fp16 copy if ws allows]
    if (have_h)
        gemm64<1, 1, 1><<<gbN, 256, 0, stream>>>(node, W_nn, nbuf, out_node, nodeh, N);
    else
        gemm64<1, 1, 0><<<gbN, 256, 0, stream>>>(node, W_nn, nbuf, out_node, nullptr, N);

    // ---------- phase 2: new_hedge = tanh((hedge@W_hh) * ((Mt-gather new_node)@W_hn)) ----------
    build_csr(hedge_idx, node_idx, NI, E, cmat, cscan, bsums, bucketed,
              csr, offs, counts, stream);
    if (have_h)
        gather_h4<<<(E + 15) / 16, 256, 0, stream>>>(nodeh, csr, offs, counts, nbuf, E);
    else
        gather_f4<<<(E + 15) / 16, 256, 0, stream>>>(out_node, csr, offs, counts, nbuf, E);
    // fused: new_hedge = tanh((agg @ W_hn) * (hedge @ W_hh)) — no f32 intermediate
    gemm64_fused<<<gbE, 256, 0, stream>>>(nbuf, W_hn, hedge, W_hh, out_hedge, E);
}

// Round 4
// 426.631 us; speedup vs baseline: 1.1229x; 1.0347x over previous
//
#include <hip/hip_runtime.h>

#define D 64
#define SH 10             // bucket = key >> SH; 1024 keys/bucket
#define BK 1024
#define NBLK 256          // blocks for sort passes A1/A2
#define PGRID 768         // persistent-GEMM grid cap

typedef _Float16 half4v __attribute__((ext_vector_type(4)));
typedef _Float16 half8 __attribute__((ext_vector_type(8)));
typedef float f32x4 __attribute__((ext_vector_type(4)));

__device__ __forceinline__ float fast_tanh(float x) {
    float e = __expf(2.f * x);
    return 1.f - 2.f * __builtin_amdgcn_rcpf(e + 1.f);
}

// Split two float4 (8 consecutive k) into fp16 hi + fp16 residual half8s.
__device__ __forceinline__ void split8(const float4& x, const float4& y,
                                       half8& h, half8& r) {
    const float* f0 = &x.x;
    const float* f1 = &y.x;
#pragma unroll
    for (int j = 0; j < 4; ++j) {
        _Float16 a = (_Float16)f0[j];
        h[j] = a; r[j] = (_Float16)(f0[j] - (float)a);
        _Float16 b = (_Float16)f1[j];
        h[j + 4] = b; r[j + 4] = (_Float16)(f1[j] - (float)b);
    }
}

// In-register 4x4 transpose across lanes u = lane&3 (regs r).
// In:  x[r] = C[row0 + 4q + r][col0 + 4g + u]
// Out: x[r] = C[row0 + 4q + u][col0 + 4g + r]
__device__ __forceinline__ void transpose4(f32x4& x, int u) {
    const bool b = (u & 1) != 0;
    float t0 = b ? x[0] : x[1];
    float t1 = b ? x[2] : x[3];
    t0 = __shfl_xor(t0, 1);
    t1 = __shfl_xor(t1, 1);
    x[0] = b ? t0 : x[0];
    x[1] = b ? x[1] : t0;
    x[2] = b ? t1 : x[2];
    x[3] = b ? x[3] : t1;
    const bool c = (u & 2) != 0;
    float s0 = c ? x[0] : x[2];
    float s1 = c ? x[1] : x[3];
    s0 = __shfl_xor(s0, 2);
    s1 = __shfl_xor(s1, 2);
    x[0] = c ? s0 : x[0];
    x[1] = c ? s1 : x[1];
    x[2] = c ? x[2] : s0;
    x[3] = c ? x[3] : s1;
}

// ---------------------------------------------------------------------------
// Persistent split-fp16 MFMA GEMM: C[M,64] = A[M,64] @ W[64,64].
// W fragments (hi+re) held in REGISTERS, loaded once per block from global
// (L2-hot). Zero LDS, zero barriers. Grid-stride over 64-row tiles.
// Epilogue: in-register 4x4 transpose -> float4 gate loads / stores.
// GATE: C = tanh(C*gate). WF: f32 out. WH: fp16 out.
// ---------------------------------------------------------------------------
template <int GATE, int WF, int WH>
__global__ __launch_bounds__(256, 3) void gemm64(const float* __restrict__ A,
                                                 const float* __restrict__ W,
                                                 const float* __restrict__ gate,
                                                 float* __restrict__ Cf,
                                                 _Float16* __restrict__ Ch,
                                                 int M, int ntiles) {
    const int tid = threadIdx.x;
    const int lane = tid & 63;
    const int rt = tid >> 6;          // wave's 16-row sub-tile
    const int m = lane & 15;          // A row in sub-tile / B col
    const int q = lane >> 4;          // k-subchunk
    const int u = m & 3, g = m >> 2;  // epilogue decomposition

    // ---- W fragments -> registers (once per block) ----
    half8 bh[2][4], br[2][4];
#pragma unroll
    for (int kc2 = 0; kc2 < 2; ++kc2) {
#pragma unroll
        for (int ct = 0; ct < 4; ++ct) {
#pragma unroll
            for (int j = 0; j < 8; ++j) {
                float w = W[(kc2 * 32 + q * 8 + j) * D + ct * 16 + m];
                _Float16 h = (_Float16)w;
                bh[kc2][ct][j] = h;
                br[kc2][ct][j] = (_Float16)(w - (float)h);
            }
        }
    }

    for (int tile = blockIdx.x; tile < ntiles; tile += gridDim.x) {
        const int base = tile * 64;

        // A direct loads (lane (m,q) owns row rt*16+m, k = q*8.. per 32-slab)
        const int arow = base + rt * 16 + m;
        const float* ap = A + (size_t)(arow < M ? arow : 0) * D + q * 8;
        float4 a0 = *(const float4*)(ap);
        float4 a1 = *(const float4*)(ap + 4);
        float4 a2 = *(const float4*)(ap + 32);
        float4 a3 = *(const float4*)(ap + 36);

        // epilogue row for this lane; gate prefetch (vectorized, early)
        const int orow = base + rt * 16 + q * 4 + u;
        const bool rok = orow < M;
        float4 gv[4];
        if (GATE) {
            const float* gp = gate + (size_t)(rok ? orow : 0) * D + g * 4;
#pragma unroll
            for (int ct = 0; ct < 4; ++ct) gv[ct] = *(const float4*)(gp + ct * 16);
        }

        half8 ah0, ar0, ah1, ar1;
        split8(a0, a1, ah0, ar0);
        split8(a2, a3, ah1, ar1);

        f32x4 acc[4] = {};
#pragma unroll
        for (int ct = 0; ct < 4; ++ct) {
            acc[ct] = __builtin_amdgcn_mfma_f32_16x16x32_f16(ah0, bh[0][ct], acc[ct], 0, 0, 0);
            acc[ct] = __builtin_amdgcn_mfma_f32_16x16x32_f16(ar0, bh[0][ct], acc[ct], 0, 0, 0);
            acc[ct] = __builtin_amdgcn_mfma_f32_16x16x32_f16(ah0, br[0][ct], acc[ct], 0, 0, 0);
            acc[ct] = __builtin_amdgcn_mfma_f32_16x16x32_f16(ah1, bh[1][ct], acc[ct], 0, 0, 0);
            acc[ct] = __builtin_amdgcn_mfma_f32_16x16x32_f16(ar1, bh[1][ct], acc[ct], 0, 0, 0);
            acc[ct] = __builtin_amdgcn_mfma_f32_16x16x32_f16(ah1, br[1][ct], acc[ct], 0, 0, 0);
        }

#pragma unroll
        for (int ct = 0; ct < 4; ++ct) transpose4(acc[ct], u);

        if (rok) {
            const size_t ro = (size_t)orow * D + g * 4;
#pragma unroll
            for (int ct = 0; ct < 4; ++ct) {
                f32x4 v = acc[ct];
                if (GATE) {
                    v[0] = fast_tanh(v[0] * gv[ct].x);
                    v[1] = fast_tanh(v[1] * gv[ct].y);
                    v[2] = fast_tanh(v[2] * gv[ct].z);
                    v[3] = fast_tanh(v[3] * gv[ct].w);
                }
                if (WF) *(f32x4*)&Cf[ro + ct * 16] = v;
                if (WH) {
                    half4v hv;
                    hv.x = (_Float16)v[0]; hv.y = (_Float16)v[1];
                    hv.z = (_Float16)v[2]; hv.w = (_Float16)v[3];
                    *(half4v*)&Ch[ro + ct * 16] = hv;
                }
            }
        }
    }
}

// Stage one 64x64 W (row-major [k][n]) into LDS as transposed [n][k] fp16
// hi (at lb) + residual (at lb+8192), XOR-swizzled: byte ^= (n&7)<<4.
__device__ __forceinline__ void stage_w(const float* __restrict__ W, char* lb,
                                        int n, int kg, int b0, int b1) {
    float wf[16];
#pragma unroll
    for (int j = 0; j < 16; ++j) wf[j] = W[(kg * 16 + j) * D + n];
    half8 h0, h1, r0, r1;
#pragma unroll
    for (int j = 0; j < 8; ++j) {
        _Float16 a = (_Float16)wf[j];
        h0[j] = a; r0[j] = (_Float16)(wf[j] - (float)a);
        _Float16 b = (_Float16)wf[j + 8];
        h1[j] = b; r1[j] = (_Float16)(wf[j + 8] - (float)b);
    }
    *(half8*)(lb + b0) = h0;
    *(half8*)(lb + b1) = h1;
    *(half8*)(lb + 8192 + b0) = r0;
    *(half8*)(lb + 8192 + b1) = r1;
}

// ---------------------------------------------------------------------------
// Fused phase-2 tail: Cf = tanh((A1@W1) * (A2@W2)). 32KB LDS (two W's),
// one tile per block; transpose epilogue -> float4 stores.
// ---------------------------------------------------------------------------
__global__ __launch_bounds__(256) void gemm64_fused(const float* __restrict__ A1,
                                                    const float* __restrict__ W1,
                                                    const float* __restrict__ A2,
                                                    const float* __restrict__ W2,
                                                    float* __restrict__ Cf, int M) {
    __shared__ _Float16 Wlds[16384];  // 32KB: W1hi,W1re,W2hi,W2re (8KB each)
    const int tid = threadIdx.x;
    const int base = blockIdx.x * 64;
    const int lane = tid & 63;
    const int rt = tid >> 6;
    const int m = lane & 15;
    const int q = lane >> 4;
    const int u = m & 3, g = m >> 2;

    const int arow = base + rt * 16 + m;
    const bool aok = arow < M;
    const size_t aoff = (size_t)(aok ? arow : 0) * D + q * 8;
    float4 p0 = *(const float4*)(A1 + aoff);
    float4 p1 = *(const float4*)(A1 + aoff + 4);
    float4 p2 = *(const float4*)(A1 + aoff + 32);
    float4 p3 = *(const float4*)(A1 + aoff + 36);
    float4 s0 = *(const float4*)(A2 + aoff);
    float4 s1 = *(const float4*)(A2 + aoff + 4);
    float4 s2 = *(const float4*)(A2 + aoff + 32);
    float4 s3 = *(const float4*)(A2 + aoff + 36);

    char* lb = (char*)Wlds;
    const int n = tid & 63, kg = tid >> 6;
    const int b0 = (n * 128 + kg * 32) ^ ((n & 7) << 4);
    const int b1 = (n * 128 + kg * 32 + 16) ^ ((n & 7) << 4);
    stage_w(W1, lb, n, kg, b0, b1);
    stage_w(W2, lb + 16384, n, kg, b0, b1);

    half8 pah0, par0, pah1, par1, sah0, sar0, sah1, sar1;
    split8(p0, p1, pah0, par0);
    split8(p2, p3, pah1, par1);
    split8(s0, s1, sah0, sar0);
    split8(s2, s3, sah1, sar1);

    __syncthreads();

    f32x4 acc1[4] = {}, acc2[4] = {};
#pragma unroll
    for (int kc2 = 0; kc2 < 2; ++kc2) {
        half8 pah = kc2 ? pah1 : pah0;
        half8 par = kc2 ? par1 : par0;
        half8 sah = kc2 ? sah1 : sah0;
        half8 sar = kc2 ? sar1 : sar0;
#pragma unroll
        for (int ct = 0; ct < 4; ++ct) {
            int n2 = ct * 16 + m;
            int boff = (n2 * 128 + kc2 * 64 + q * 16) ^ ((n2 & 7) << 4);
            half8 bh = *(const half8*)(lb + boff);
            half8 br = *(const half8*)(lb + 8192 + boff);
            acc1[ct] = __builtin_amdgcn_mfma_f32_16x16x32_f16(pah, bh, acc1[ct], 0, 0, 0);
            acc1[ct] = __builtin_amdgcn_mfma_f32_16x16x32_f16(par, bh, acc1[ct], 0, 0, 0);
            acc1[ct] = __builtin_amdgcn_mfma_f32_16x16x32_f16(pah, br, acc1[ct], 0, 0, 0);
            half8 ch = *(const half8*)(lb + 16384 + boff);
            half8 cr = *(const half8*)(lb + 24576 + boff);
            acc2[ct] = __builtin_amdgcn_mfma_f32_16x16x32_f16(sah, ch, acc2[ct], 0, 0, 0);
            acc2[ct] = __builtin_amdgcn_mfma_f32_16x16x32_f16(sar, ch, acc2[ct], 0, 0, 0);
            acc2[ct] = __builtin_amdgcn_mfma_f32_16x16x32_f16(sah, cr, acc2[ct], 0, 0, 0);
        }
    }

#pragma unroll
    for (int ct = 0; ct < 4; ++ct) {
        transpose4(acc1[ct], u);
        transpose4(acc2[ct], u);
    }

    const int orow = base + rt * 16 + q * 4 + u;
    if (orow < M) {
        const size_t ro = (size_t)orow * D + g * 4;
#pragma unroll
        for (int ct = 0; ct < 4; ++ct) {
            f32x4 v;
            v[0] = fast_tanh(acc1[ct][0] * acc2[ct][0]);
            v[1] = fast_tanh(acc1[ct][1] * acc2[ct][1]);
            v[2] = fast_tanh(acc1[ct][2] * acc2[ct][2]);
            v[3] = fast_tanh(acc1[ct][3] * acc2[ct][3]);
            *(f32x4*)&Cf[ro + ct * 16] = v;
        }
    }
}

// --------------------- zero-global-atomic counting sort ---------------------
__global__ __launch_bounds__(256) void sort_hist(const int* __restrict__ keys,
                                                 int* __restrict__ cmat,
                                                 int n, int B, int ipb) {
    __shared__ int h[256];
    const int tid = threadIdx.x;
    for (int i = tid; i < B; i += 256) h[i] = 0;
    __syncthreads();
    const int start = blockIdx.x * ipb;
    const int end = (start + ipb < n) ? start + ipb : n;
    for (int i = start + tid; i < end; i += 256)
        atomicAdd(&h[keys[i] >> SH], 1);
    __syncthreads();
    for (int b = tid; b < B; b += 256) cmat[b * NBLK + blockIdx.x] = h[b];
}

__global__ __launch_bounds__(256) void scan1(const int* __restrict__ src,
                                             int* __restrict__ dst,
                                             int* __restrict__ bsums, int n) {
    __shared__ int s[256];
    const int t = threadIdx.x;
    const int base = blockIdx.x * 1024 + t * 4;
    int v[4];
#pragma unroll
    for (int j = 0; j < 4; ++j) v[j] = (base + j < n) ? src[base + j] : 0;
    int tsum = v[0] + v[1] + v[2] + v[3];
    s[t] = tsum;
    __syncthreads();
    for (int o = 1; o < 256; o <<= 1) {
        int x = (t >= o) ? s[t - o] : 0;
        __syncthreads();
        s[t] += x;
        __syncthreads();
    }
    int run = s[t] - tsum;
    if (t == 255) bsums[blockIdx.x] = s[255];
#pragma unroll
    for (int j = 0; j < 4; ++j) {
        if (base + j < n) dst[base + j] = run;
        run += v[j];
    }
}

// Fused scan2+scan3.
__global__ __launch_bounds__(256) void scan23(int* __restrict__ a,
                                              const int* __restrict__ bsums,
                                              int n, int nb) {
    __shared__ int sb[256];
    const int t = threadIdx.x;
    int v = (t < nb) ? bsums[t] : 0;
    sb[t] = v;
    __syncthreads();
    for (int o = 1; o < 256; o <<= 1) {
        int x = (t >= o) ? sb[t - o] : 0;
        __syncthreads();
        sb[t] += x;
        __syncthreads();
    }
    int incl = sb[t];
    __syncthreads();
    sb[t] = incl - v;          // exclusive block prefix
    __syncthreads();
    int i = blockIdx.x * 256 + t;
    if (i < n) a[i] += sb[i >> 10];
}

__global__ __launch_bounds__(256) void sort_scatter(const int* __restrict__ keys,
                                                    const int* __restrict__ vals,
                                                    const int* __restrict__ cscan,
                                                    int* __restrict__ bucketed,
                                                    int n, int B, int ipb) {
    __shared__ int cur[256];
    const int tid = threadIdx.x;
    for (int i = tid; i < B; i += 256) cur[i] = cscan[i * NBLK + blockIdx.x];
    __syncthreads();
    const int start = blockIdx.x * ipb;
    const int end = (start + ipb < n) ? start + ipb : n;
    for (int i = start + tid; i < end; i += 256) {
        int k = keys[i];
        int p = atomicAdd(&cur[k >> SH], 1);
        bucketed[p] = (vals[i] << SH) | (k & (BK - 1));
    }
}

// Pass B: per-bucket exact CSR, 1024 keys/bucket
__global__ __launch_bounds__(256) void sort_finalize(const int* __restrict__ bucketed,
                                                     const int* __restrict__ cscan,
                                                     int* __restrict__ csr,
                                                     int* __restrict__ offs,
                                                     int* __restrict__ counts,
                                                     int n, int B, int nkeys) {
    __shared__ int h[BK];
    __shared__ int s[256];
    const int t = threadIdx.x;
    const int b = blockIdx.x;
    const int bstart = cscan[b * NBLK];
    const int bend = (b + 1 < B) ? cscan[(b + 1) * NBLK] : n;

    for (int i = t; i < BK; i += 256) h[i] = 0;
    __syncthreads();
    for (int i = bstart + t; i < bend; i += 256)
        atomicAdd(&h[bucketed[i] & (BK - 1)], 1);
    __syncthreads();
    const int c0 = h[t * 4], c1 = h[t * 4 + 1], c2 = h[t * 4 + 2], c3 = h[t * 4 + 3];
    const int tsum = c0 + c1 + c2 + c3;
    s[t] = tsum;
    __syncthreads();
    for (int o = 1; o < 256; o <<= 1) {
        int x = (t >= o) ? s[t - o] : 0;
        __syncthreads();
        s[t] += x;
        __syncthreads();
    }
    const int e0 = s[t] - tsum;
    const int e1 = e0 + c0, e2 = e1 + c1, e3 = e2 + c2;
    const int keyb = b * BK + t * 4;
    if (keyb + 0 < nkeys) { offs[keyb + 0] = bstart + e0; counts[keyb + 0] = c0; }
    if (keyb + 1 < nkeys) { offs[keyb + 1] = bstart + e1; counts[keyb + 1] = c1; }
    if (keyb + 2 < nkeys) { offs[keyb + 2] = bstart + e2; counts[keyb + 2] = c2; }
    if (keyb + 3 < nkeys) { offs[keyb + 3] = bstart + e3; counts[keyb + 3] = c3; }
    h[t * 4 + 0] = bstart + e0;
    h[t * 4 + 1] = bstart + e1;
    h[t * 4 + 2] = bstart + e2;
    h[t * 4 + 3] = bstart + e3;
    __syncthreads();
    for (int i = bstart + t; i < bend; i += 256) {
        int e = bucketed[i];
        int p = atomicAdd(&h[e & (BK - 1)], 1);
        csr[p] = e >> SH;
    }
}

// ---------------------------------------------------------------------------
// Gather: one 16-lane group per dst row (16 rows/block), 4-deep unroll.
// ---------------------------------------------------------------------------
__global__ __launch_bounds__(256) void gather_h4(const _Float16* __restrict__ src,
                                                 const int* __restrict__ csr,
                                                 const int* __restrict__ offs,
                                                 const int* __restrict__ counts,
                                                 float* __restrict__ dst, int nrows) {
    const int row = blockIdx.x * 16 + (threadIdx.x >> 4);
    const int sub = threadIdx.x & 15;
    if (row >= nrows) return;
    const int start = offs[row];
    const int end = start + counts[row];

    f32x4 a0 = {}, a1 = {}, a2 = {}, a3 = {};
    int j = start;
    for (; j + 3 < end; j += 4) {
        int c0 = csr[j], c1 = csr[j + 1], c2 = csr[j + 2], c3 = csr[j + 3];
        half4v v0 = *(const half4v*)&src[((size_t)c0 << 6) + sub * 4];
        half4v v1 = *(const half4v*)&src[((size_t)c1 << 6) + sub * 4];
        half4v v2 = *(const half4v*)&src[((size_t)c2 << 6) + sub * 4];
        half4v v3 = *(const half4v*)&src[((size_t)c3 << 6) + sub * 4];
        a0 += __builtin_convertvector(v0, f32x4);
        a1 += __builtin_convertvector(v1, f32x4);
        a2 += __builtin_convertvector(v2, f32x4);
        a3 += __builtin_convertvector(v3, f32x4);
    }
    for (; j < end; ++j) {
        int c = csr[j];
        half4v v = *(const half4v*)&src[((size_t)c << 6) + sub * 4];
        a0 += __builtin_convertvector(v, f32x4);
    }
    f32x4 r = (a0 + a1) + (a2 + a3);
    __builtin_nontemporal_store(r, (f32x4*)&dst[((size_t)row << 6) + sub * 4]);
}

__global__ __launch_bounds__(256) void gather_f4(const float* __restrict__ src,
                                                 const int* __restrict__ csr,
                                                 const int* __restrict__ offs,
                                                 const int* __restrict__ counts,
                                                 float* __restrict__ dst, int nrows) {
    const int row = blockIdx.x * 16 + (threadIdx.x >> 4);
    const int sub = threadIdx.x & 15;
    if (row >= nrows) return;
    const int start = offs[row];
    const int end = start + counts[row];

    f32x4 a0 = {}, a1 = {}, a2 = {}, a3 = {};
    int j = start;
    for (; j + 3 < end; j += 4) {
        int c0 = csr[j], c1 = csr[j + 1], c2 = csr[j + 2], c3 = csr[j + 3];
        f32x4 v0 = *(const f32x4*)&src[((size_t)c0 << 6) + sub * 4];
        f32x4 v1 = *(const f32x4*)&src[((size_t)c1 << 6) + sub * 4];
        f32x4 v2 = *(const f32x4*)&src[((size_t)c2 << 6) + sub * 4];
        f32x4 v3 = *(const f32x4*)&src[((size_t)c3 << 6) + sub * 4];
        a0 += v0; a1 += v1; a2 += v2; a3 += v3;
    }
    for (; j < end; ++j) {
        int c = csr[j];
        a0 += *(const f32x4*)&src[((size_t)c << 6) + sub * 4];
    }
    f32x4 r = (a0 + a1) + (a2 + a3);
    __builtin_nontemporal_store(r, (f32x4*)&dst[((size_t)row << 6) + sub * 4]);
}

static void build_csr(const int* keys, const int* vals, int NI, int nkeys,
                      int* cmat, int* cscan, int* bsums, int* bucketed,
                      int* csr, int* offs, int* counts, hipStream_t stream) {
    const int B = (nkeys + BK - 1) >> SH;
    const int L = B * NBLK;
    const int ipb = (NI + NBLK - 1) / NBLK;
    const int nsb = (L + 1023) / 1024;
    sort_hist<<<NBLK, 256, 0, stream>>>(keys, cmat, NI, B, ipb);
    scan1<<<nsb, 256, 0, stream>>>(cmat, cscan, bsums, L);
    scan23<<<(L + 255) / 256, 256, 0, stream>>>(cscan, bsums, L, nsb);
    sort_scatter<<<NBLK, 256, 0, stream>>>(keys, vals, cscan, bucketed, NI, B, ipb);
    sort_finalize<<<B, 256, 0, stream>>>(bucketed, cscan, csr, offs, counts, NI, B, nkeys);
}

extern "C" void kernel_launch(void* const* d_in, const int* in_sizes, int n_in,
                              void* d_out, int out_size, void* d_ws, size_t ws_size,
                              hipStream_t stream) {
    const float* node  = (const float*)d_in[0];
    const float* hedge = (const float*)d_in[1];
    const float* W_nn  = (const float*)d_in[2];
    const float* W_nh  = (const float*)d_in[3];
    const float* W_hh  = (const float*)d_in[4];
    const float* W_hn  = (const float*)d_in[5];
    const int* node_idx  = (const int*)d_in[6];
    const int* hedge_idx = (const int*)d_in[7];

    const int N  = in_sizes[0] / D;   // 200,000
    const int E  = in_sizes[1] / D;   // 100,000
    const int NI = in_sizes[6];       // 1,600,000
    const int maxNE = (N > E) ? N : E;
    const int maxB = (maxNE + BK - 1) >> SH;

    float* out_node  = (float*)d_out;                  // [N,64]
    float* out_hedge = out_node + (size_t)N * D;       // [E,64] (scratch: hproj fp16)

    float*     nbuf     = (float*)d_ws;                // ngate / agg (f32)
    int*       bucketed = (int*)(nbuf + (size_t)N * D);
    int*       csr      = bucketed + NI;
    int*       cmat     = csr + NI;
    int*       cscan    = cmat + (size_t)maxB * NBLK;
    int*       offs     = cscan + (size_t)maxB * NBLK;
    int*       counts   = offs + maxNE;
    int*       bsums    = counts + maxNE;
    _Float16*  nodeh    = (_Float16*)(bsums + 256);

    const size_t need = (size_t)((char*)(nodeh + (size_t)N * D) - (char*)d_ws);
    const bool have_h = ws_size >= need;

    const int gbE = (E + 63) / 64;
    const int gbN = (N + 63) / 64;
    const int GE = gbE < PGRID ? gbE : PGRID;
    const int GN = gbN < PGRID ? gbN : PGRID;

    // ---------- phase 1: ngate = Mt-gather(hproj) ----------
    build_csr(node_idx, hedge_idx, NI, N, cmat, cscan, bsums, bucketed,
              csr, offs, counts, stream);
    // hproj = hedge @ W_nh (fp16 into out_hedge scratch)
    gemm64<0, 0, 1><<<GE, 256, 0, stream>>>(hedge, W_nh, nullptr, nullptr,
                                            (_Float16*)out_hedge, E, gbE);
    gather_h4<<<(N + 15) / 16, 256, 0, stream>>>((const _Float16*)out_hedge, csr, offs,
                                                 counts, nbuf, N);
    // new_node = tanh((node@W_nn)*ngate)  [+ fp16 copy if ws allows]
    if (have_h)
        gemm64<1, 1, 1><<<GN, 256, 0, stream>>>(node, W_nn, nbuf, out_node, nodeh, N, gbN);
    else
        gemm64<1, 1, 0><<<GN, 256, 0, stream>>>(node, W_nn, nbuf, out_node, nullptr, N, gbN);

    // ---------- phase 2: new_hedge = tanh((hedge@W_hh) * ((Mt-gather new_node)@W_hn)) ----------
    build_csr(hedge_idx, node_idx, NI, E, cmat, cscan, bsums, bucketed,
              csr, offs, counts, stream);
    if (have_h)
        gather_h4<<<(E + 15) / 16, 256, 0, stream>>>(nodeh, csr, offs, counts, nbuf, E);
    else
        gather_f4<<<(E + 15) / 16, 256, 0, stream>>>(out_node, csr, offs, counts, nbuf, E);
    // fused: new_hedge = tanh((agg @ W_hn) * (hedge @ W_hh)) — no f32 intermediate
    gemm64_fused<<<gbE, 256, 0, stream>>>(nbuf, W_hn, hedge, W_hh, out_hedge, E);
}